// Round 1
// baseline (918.704 us; speedup 1.0000x reference)
//
#include <hip/hip_runtime.h>
#include <math.h>

#define HDIM 1024
#define FDIM 2048   // 2H
#define NEXP 8
#define MTOK 16384  // 8*2048 tokens
#define NBLK 16     // FDIM / 128

// Kernel 1: C = gelu(x @ w1 + b1) for a 128x128 tile, then immediately
// reduce against w2[128-slice, 8] -> deterministic partial logits.
// Never materializes h (saves 134 MB of traffic).
__global__ __launch_bounds__(256) void router_gemm1(
    const float* __restrict__ x, const float* __restrict__ w1,
    const float* __restrict__ b1, const float* __restrict__ w2,
    float* __restrict__ part)
{
    __shared__ __align__(16) float As[8][128];
    __shared__ __align__(16) float Bs[8][128];

    const int tid = threadIdx.x;
    const int tx = tid & 15;        // 0..15 -> n microtile
    const int ty = tid >> 4;        // 0..15 -> m microtile
    const int bn = blockIdx.x;      // 0..15  (n-block over FDIM)
    const int bm = blockIdx.y;      // 0..127 (m-block over tokens)
    const int m0 = bm * 128, n0 = bn * 128;

    float c[8][8];
    #pragma unroll
    for (int i = 0; i < 8; i++)
        #pragma unroll
        for (int j = 0; j < 8; j++) c[i][j] = 0.0f;

    // A-tile load mapping: 128 rows x 8 k, one float4 per thread
    const int a_r = tid >> 1;           // 0..127
    const int a_c = (tid & 1) * 4;      // 0 or 4
    // B-tile load mapping: 8 k-rows x 128 n, one float4 per thread
    const int b_r = tid >> 5;           // 0..7
    const int b_c = (tid & 31) * 4;     // 0..124

    const float* aptr = x + (size_t)(m0 + a_r) * HDIM + a_c;
    const float* bptr = w1 + (size_t)b_r * FDIM + n0 + b_c;

    for (int k0 = 0; k0 < HDIM; k0 += 8) {
        float4 av = *(const float4*)(aptr + k0);
        float4 bv = *(const float4*)(bptr + (size_t)k0 * FDIM);
        __syncthreads();
        As[a_c + 0][a_r] = av.x;
        As[a_c + 1][a_r] = av.y;
        As[a_c + 2][a_r] = av.z;
        As[a_c + 3][a_r] = av.w;
        *(float4*)(&Bs[b_r][b_c]) = bv;
        __syncthreads();
        #pragma unroll
        for (int k = 0; k < 8; k++) {
            float4 a0 = *(const float4*)(&As[k][ty * 8]);
            float4 a1 = *(const float4*)(&As[k][ty * 8 + 4]);
            float4 bq0 = *(const float4*)(&Bs[k][tx * 8]);
            float4 bq1 = *(const float4*)(&Bs[k][tx * 8 + 4]);
            float a[8] = {a0.x, a0.y, a0.z, a0.w, a1.x, a1.y, a1.z, a1.w};
            float b[8] = {bq0.x, bq0.y, bq0.z, bq0.w, bq1.x, bq1.y, bq1.z, bq1.w};
            #pragma unroll
            for (int i = 0; i < 8; i++)
                #pragma unroll
                for (int j = 0; j < 8; j++)
                    c[i][j] += a[i] * b[j];
        }
    }

    // epilogue: bias + exact GELU (matches jax.nn.gelu approximate=False)
    #pragma unroll
    for (int j = 0; j < 8; j++) {
        float bb = b1[n0 + tx * 8 + j];
        #pragma unroll
        for (int i = 0; i < 8; i++) {
            float v = c[i][j] + bb;
            c[i][j] = 0.5f * v * (1.0f + erff(v * 0.70710678118654752f));
        }
    }

    // stage this block's w2 slice [128 rows x 8 experts] into LDS (reuse As)
    __syncthreads();
    float* wsh = &As[0][0];  // 1024 floats
    ((float4*)wsh)[tid] = *(const float4*)(w2 + (size_t)n0 * NEXP + tid * 4);
    __syncthreads();

    // per-expert partial: sum over this block's 128 f-columns
    #pragma unroll
    for (int e = 0; e < NEXP; e++) {
        float p[8];
        #pragma unroll
        for (int i = 0; i < 8; i++) p[i] = 0.0f;
        #pragma unroll
        for (int j = 0; j < 8; j++) {
            float w = wsh[(tx * 8 + j) * NEXP + e];
            #pragma unroll
            for (int i = 0; i < 8; i++) p[i] += c[i][j] * w;
        }
        // butterfly reduce across the 16 tx-lanes (same wave: tids ty*16..+15)
        #pragma unroll
        for (int off = 1; off < 16; off <<= 1) {
            #pragma unroll
            for (int i = 0; i < 8; i++) p[i] += __shfl_xor(p[i], off);
        }
        if (tx == 0) {
            #pragma unroll
            for (int i = 0; i < 8; i++) {
                int t = m0 + ty * 8 + i;
                part[(size_t)bn * (MTOK * NEXP) + (size_t)t * NEXP + e] = p[i];
            }
        }
    }
}

// Kernel 2: deterministic partial-sum -> logits, top-2, softmax, masks,
// usage/count block-reduced into global accumulators.
__global__ __launch_bounds__(256) void router_topk(
    const float* __restrict__ part, const float* __restrict__ b2,
    float* __restrict__ out, float* __restrict__ gu, int* __restrict__ gc)
{
    const int t = blockIdx.x * 256 + threadIdx.x;

    float logit[8];
    #pragma unroll
    for (int e = 0; e < 8; e++) logit[e] = b2[e];
    #pragma unroll
    for (int j = 0; j < NBLK; j++) {
        const float4* p4 = (const float4*)(part + (size_t)j * (MTOK * NEXP) + (size_t)t * NEXP);
        float4 u = p4[0], v = p4[1];
        logit[0] += u.x; logit[1] += u.y; logit[2] += u.z; logit[3] += u.w;
        logit[4] += v.x; logit[5] += v.y; logit[6] += v.z; logit[7] += v.w;
    }

    // top-2 with lowest-index tie-break (strict >), matching lax.top_k
    int i1 = 0; float v1 = logit[0];
    #pragma unroll
    for (int e = 1; e < 8; e++) { if (logit[e] > v1) { v1 = logit[e]; i1 = e; } }
    int i2 = -1; float v2 = -INFINITY;
    #pragma unroll
    for (int e = 0; e < 8; e++) {
        if (e != i1 && logit[e] > v2) { v2 = logit[e]; i2 = e; }
    }
    // softmax over (v1, v2); v1 >= v2
    float ex = expf(v2 - v1);
    float inv = 1.0f / (1.0f + ex);
    float wa = inv;          // weight for i1
    float wb = ex * inv;     // weight for i2

    // expert_weights
    float4* o = (float4*)(out + (size_t)t * NEXP);
    o[0] = make_float4(logit[0], logit[1], logit[2], logit[3]);
    o[1] = make_float4(logit[4], logit[5], logit[6], logit[7]);

    // masks
    float mk[8];
    #pragma unroll
    for (int e = 0; e < 8; e++) mk[e] = 0.0f;
    mk[i1] = wa; mk[i2] = wb;
    float4* om = (float4*)(out + (size_t)(MTOK * NEXP) + (size_t)t * NEXP);
    om[0] = make_float4(mk[0], mk[1], mk[2], mk[3]);
    om[1] = make_float4(mk[4], mk[5], mk[6], mk[7]);

    // usage / sparsity-count reduction: LDS first, one global atomic per block
    __shared__ float us[8];
    __shared__ int cs;
    if (threadIdx.x < 8) us[threadIdx.x] = 0.0f;
    if (threadIdx.x == 0) cs = 0;
    __syncthreads();
    atomicAdd(&us[i1], wa);
    atomicAdd(&us[i2], wb);
    int cnt = (wa > 0.0f ? 1 : 0) + (wb > 0.0f ? 1 : 0);
    atomicAdd(&cs, cnt);
    __syncthreads();
    if (threadIdx.x < 8) atomicAdd(&gu[threadIdx.x], us[threadIdx.x]);
    if (threadIdx.x == 0) atomicAdd(gc, cs);
}

// Kernel 3: finalize losses + normalized usage.
__global__ void router_final(const float* __restrict__ gu, const int* __restrict__ gc,
                             float* __restrict__ out)
{
    if (blockIdx.x == 0 && threadIdx.x == 0) {
        float u[8]; float tot = 0.0f;
        for (int e = 0; e < 8; e++) { u[e] = gu[e]; tot += u[e]; }
        float lb = 0.0f;
        for (int e = 0; e < 8; e++) {
            float un = u[e] / tot;
            out[2 * MTOK * NEXP + 1 + e] = un;
            float d = un - 0.125f;
            lb += d * d;
        }
        lb *= (1.0f / 8.0f);
        float sp = ((float)(*gc) / (float)MTOK) * 0.5f;  // mean(count)/TOP_K
        out[2 * MTOK * NEXP] = lb + 0.1f * sp;
    }
}

extern "C" void kernel_launch(void* const* d_in, const int* in_sizes, int n_in,
                              void* d_out, int out_size, void* d_ws, size_t ws_size,
                              hipStream_t stream) {
    const float* x  = (const float*)d_in[0];
    const float* w1 = (const float*)d_in[1];
    const float* b1 = (const float*)d_in[2];
    const float* w2 = (const float*)d_in[3];
    const float* b2 = (const float*)d_in[4];
    float* out = (float*)d_out;

    float* part = (float*)d_ws;                       // 16 * 16384 * 8 floats = 8 MB
    float* gu = part + (size_t)NBLK * MTOK * NEXP;    // 8 floats usage
    int* gc = (int*)(gu + 8);                         // 1 int count

    hipMemsetAsync(gu, 0, 64, stream);  // zero accumulators (ws is poisoned)

    dim3 g1(NBLK, MTOK / 128);
    router_gemm1<<<g1, 256, 0, stream>>>(x, w1, b1, w2, part);
    router_topk<<<MTOK / 256, 256, 0, stream>>>(part, b2, out, gu, gc);
    router_final<<<1, 64, 0, stream>>>(gu, gc, out);
}

// Round 3
// 552.368 us; speedup vs baseline: 1.6632x; 1.6632x over previous
//
#include <hip/hip_runtime.h>
#include <math.h>

#define HDIM 1024
#define FDIM 2048   // 2H
#define NEXP 8
#define MTOK 16384  // 8*2048 tokens
#define NSLC 32     // partial-logit slices: 16 n-blocks x 2 wn-waves

typedef __attribute__((ext_vector_type(8))) short bf16x8;   // 8 bf16 = 4 VGPRs
typedef __attribute__((ext_vector_type(4))) float f32x4;

__device__ inline unsigned short f2bf_rne(float f) {
    unsigned int u = __float_as_uint(f);
    u = (u + 0x7FFFu + ((u >> 16) & 1u)) >> 16;
    return (unsigned short)u;
}
__device__ inline float bf2f(unsigned short h) {
    unsigned int u = ((unsigned int)h) << 16;
    return __uint_as_float(u);
}

// --- Kernel A: x fp32 -> (xh, xl) bf16 split: x ~= xh + xl, |xl|<=2^-9|x| ---
__global__ __launch_bounds__(256) void cvt_x(const float* __restrict__ x,
                                             unsigned short* __restrict__ xh,
                                             unsigned short* __restrict__ xl)
{
    size_t i = ((size_t)blockIdx.x * 256 + threadIdx.x) * 8;
    float v[8];
    *(float4*)(v)     = *(const float4*)(x + i);
    *(float4*)(v + 4) = *(const float4*)(x + i + 4);
    union { unsigned short u[8]; uint4 q; } oh, ol;
    #pragma unroll
    for (int j = 0; j < 8; j++) {
        unsigned short h = f2bf_rne(v[j]);
        oh.u[j] = h;
        ol.u[j] = f2bf_rne(v[j] - bf2f(h));
    }
    *(uint4*)(xh + i) = oh.q;
    *(uint4*)(xl + i) = ol.q;
}

// --- Kernel B: w1 [K][N] fp32 -> transposed bf16 split w1th/w1tl [N][K] ---
__global__ __launch_bounds__(256) void cvt_w1t(const float* __restrict__ w1,
                                               unsigned short* __restrict__ w1th,
                                               unsigned short* __restrict__ w1tl)
{
    __shared__ float t[32][33];
    int n0 = blockIdx.x * 32;   // over FDIM
    int k0 = blockIdx.y * 32;   // over HDIM
    int lx = threadIdx.x & 31, ly = threadIdx.x >> 5;  // 32 x 8
    #pragma unroll
    for (int r = 0; r < 32; r += 8)
        t[ly + r][lx] = w1[(size_t)(k0 + ly + r) * FDIM + n0 + lx];
    __syncthreads();
    #pragma unroll
    for (int r = 0; r < 32; r += 8) {
        float v = t[lx][ly + r];
        unsigned short h = f2bf_rne(v);
        unsigned short l = f2bf_rne(v - bf2f(h));
        size_t o = (size_t)(n0 + ly + r) * HDIM + k0 + lx;
        w1th[o] = h;
        w1tl[o] = l;
    }
}

// --- Kernel C: split-bf16 MFMA GEMM1 (fp32-class precision) + GELU + w2 ---
// C-tile 128x128/block, 4 waves 2x2, each 64x64 via 4x4 frags of 16x16x32.
// Per K-chunk: acc += ah*bh + ah*bl + al*bh  (xl*wl dropped: 2^-18 rel).
// Staging via global_load_lds w=16, XOR swizzle ch(m,k8)=m*4+(k8^(m&3)).
#define BM 128
#define BN 128
#define BK 32

__global__ __launch_bounds__(256) void gemm1_mfma(
    const unsigned short* __restrict__ xh, const unsigned short* __restrict__ xl,
    const unsigned short* __restrict__ w1th, const unsigned short* __restrict__ w1tl,
    const float* __restrict__ b1, const float* __restrict__ w2,
    float* __restrict__ part)
{
    __shared__ __align__(16) short Ash[BM * BK];  // 8 KB each
    __shared__ __align__(16) short Asl[BM * BK];
    __shared__ __align__(16) short Bsh[BN * BK];
    __shared__ __align__(16) short Bsl[BN * BK];

    const int tid  = threadIdx.x;
    const int lane = tid & 63;
    const int l15  = lane & 15;
    const int q    = lane >> 4;
    const int wave = tid >> 6;
    const int wm   = wave & 1;
    const int wn   = wave >> 1;
    const int bn = blockIdx.x, bm = blockIdx.y;
    const int m0 = bm * BM, n0 = bn * BN;

    f32x4 acc[4][4];
    #pragma unroll
    for (int i = 0; i < 4; i++)
        #pragma unroll
        for (int j = 0; j < 4; j++) acc[i][j] = (f32x4){0.f, 0.f, 0.f, 0.f};

    for (int k0 = 0; k0 < HDIM; k0 += BK) {
        __syncthreads();  // prior iter done reading LDS
        #pragma unroll
        for (int r = 0; r < 2; r++) {
            int c = r * 256 + tid;                 // chunk 0..511
            int m = c >> 2;
            int k8 = (c & 3) ^ (m & 3);
            size_t ao = (size_t)(m0 + m) * HDIM + k0 + k8 * 8;
            size_t bo = (size_t)(n0 + m) * HDIM + k0 + k8 * 8;
            int lo = c * 8;                        // shorts
            __builtin_amdgcn_global_load_lds(
                (const __attribute__((address_space(1))) void*)(xh + ao),
                (__attribute__((address_space(3))) void*)&Ash[lo], 16, 0, 0);
            __builtin_amdgcn_global_load_lds(
                (const __attribute__((address_space(1))) void*)(xl + ao),
                (__attribute__((address_space(3))) void*)&Asl[lo], 16, 0, 0);
            __builtin_amdgcn_global_load_lds(
                (const __attribute__((address_space(1))) void*)(w1th + bo),
                (__attribute__((address_space(3))) void*)&Bsh[lo], 16, 0, 0);
            __builtin_amdgcn_global_load_lds(
                (const __attribute__((address_space(1))) void*)(w1tl + bo),
                (__attribute__((address_space(3))) void*)&Bsl[lo], 16, 0, 0);
        }
        __syncthreads();  // drains vmcnt before LDS reads

        bf16x8 ah[4], al[4], bh[4], bl[4];
        #pragma unroll
        for (int i = 0; i < 4; i++) {
            int m = wm * 64 + i * 16 + l15;
            int ch = m * 4 + (q ^ (m & 3));
            ah[i] = *(const bf16x8*)&Ash[ch * 8];
            al[i] = *(const bf16x8*)&Asl[ch * 8];
        }
        #pragma unroll
        for (int j = 0; j < 4; j++) {
            int n = wn * 64 + j * 16 + l15;
            int ch = n * 4 + (q ^ (n & 3));
            bh[j] = *(const bf16x8*)&Bsh[ch * 8];
            bl[j] = *(const bf16x8*)&Bsl[ch * 8];
        }
        #pragma unroll
        for (int i = 0; i < 4; i++)
            #pragma unroll
            for (int j = 0; j < 4; j++) {
                acc[i][j] = __builtin_amdgcn_mfma_f32_16x16x32_bf16(
                    ah[i], bh[j], acc[i][j], 0, 0, 0);
                acc[i][j] = __builtin_amdgcn_mfma_f32_16x16x32_bf16(
                    ah[i], bl[j], acc[i][j], 0, 0, 0);
                acc[i][j] = __builtin_amdgcn_mfma_f32_16x16x32_bf16(
                    al[i], bh[j], acc[i][j], 0, 0, 0);
            }
    }

    // --- epilogue: bias + exact GELU (C/D: col=lane&15, row=q*4+r) ---
    #pragma unroll
    for (int j = 0; j < 4; j++) {
        int n = n0 + wn * 64 + j * 16 + l15;
        float bb = b1[n];
        #pragma unroll
        for (int i = 0; i < 4; i++)
            #pragma unroll
            for (int r = 0; r < 4; r++) {
                float v = acc[i][j][r] + bb;
                acc[i][j][r] = 0.5f * v * (1.0f + erff(v * 0.70710678118654752f));
            }
    }

    // w2 rows for this lane's 4 columns
    float w2r[4][8];
    #pragma unroll
    for (int j = 0; j < 4; j++) {
        const float4* p = (const float4*)(w2 + (size_t)(n0 + wn * 64 + j * 16 + l15) * NEXP);
        float4 u = p[0], v = p[1];
        w2r[j][0] = u.x; w2r[j][1] = u.y; w2r[j][2] = u.z; w2r[j][3] = u.w;
        w2r[j][4] = v.x; w2r[j][5] = v.y; w2r[j][6] = v.z; w2r[j][7] = v.w;
    }

    const int sl = bn * 2 + wn;  // partial slice (deterministic)
    #pragma unroll
    for (int e = 0; e < NEXP; e++) {
        float p[4][4];
        #pragma unroll
        for (int i = 0; i < 4; i++)
            #pragma unroll
            for (int r = 0; r < 4; r++) {
                float s = 0.f;
                #pragma unroll
                for (int j = 0; j < 4; j++) s += acc[i][j][r] * w2r[j][e];
                p[i][r] = s;
            }
        #pragma unroll
        for (int off = 1; off < 16; off <<= 1)
            #pragma unroll
            for (int i = 0; i < 4; i++)
                #pragma unroll
                for (int r = 0; r < 4; r++)
                    p[i][r] += __shfl_xor(p[i][r], off);
        if (l15 == 0) {
            #pragma unroll
            for (int i = 0; i < 4; i++)
                #pragma unroll
                for (int r = 0; r < 4; r++) {
                    int m = m0 + wm * 64 + i * 16 + q * 4 + r;
                    part[(size_t)sl * (MTOK * NEXP) + (size_t)m * NEXP + e] = p[i][r];
                }
        }
    }
}

// --- Kernel 2: deterministic sum of 32 slices -> logits, top-2, softmax ---
__global__ __launch_bounds__(256) void router_topk(
    const float* __restrict__ part, const float* __restrict__ b2,
    float* __restrict__ out, float* __restrict__ gu, int* __restrict__ gc)
{
    const int t = blockIdx.x * 256 + threadIdx.x;

    float logit[8];
    #pragma unroll
    for (int e = 0; e < 8; e++) logit[e] = b2[e];
    #pragma unroll
    for (int j = 0; j < NSLC; j++) {
        const float4* p4 = (const float4*)(part + (size_t)j * (MTOK * NEXP) + (size_t)t * NEXP);
        float4 u = p4[0], v = p4[1];
        logit[0] += u.x; logit[1] += u.y; logit[2] += u.z; logit[3] += u.w;
        logit[4] += v.x; logit[5] += v.y; logit[6] += v.z; logit[7] += v.w;
    }

    int i1 = 0; float v1 = logit[0];
    #pragma unroll
    for (int e = 1; e < 8; e++) { if (logit[e] > v1) { v1 = logit[e]; i1 = e; } }
    int i2 = -1; float v2 = -INFINITY;
    #pragma unroll
    for (int e = 0; e < 8; e++) {
        if (e != i1 && logit[e] > v2) { v2 = logit[e]; i2 = e; }
    }
    float ex = expf(v2 - v1);
    float inv = 1.0f / (1.0f + ex);
    float wa = inv, wb = ex * inv;

    float4* o = (float4*)(out + (size_t)t * NEXP);
    o[0] = make_float4(logit[0], logit[1], logit[2], logit[3]);
    o[1] = make_float4(logit[4], logit[5], logit[6], logit[7]);

    float mk[8];
    #pragma unroll
    for (int e = 0; e < 8; e++) mk[e] = 0.0f;
    mk[i1] = wa; mk[i2] = wb;
    float4* om = (float4*)(out + (size_t)(MTOK * NEXP) + (size_t)t * NEXP);
    om[0] = make_float4(mk[0], mk[1], mk[2], mk[3]);
    om[1] = make_float4(mk[4], mk[5], mk[6], mk[7]);

    __shared__ float us[8];
    __shared__ int cs;
    if (threadIdx.x < 8) us[threadIdx.x] = 0.0f;
    if (threadIdx.x == 0) cs = 0;
    __syncthreads();
    atomicAdd(&us[i1], wa);
    atomicAdd(&us[i2], wb);
    int cnt = (wa > 0.0f ? 1 : 0) + (wb > 0.0f ? 1 : 0);
    atomicAdd(&cs, cnt);
    __syncthreads();
    if (threadIdx.x < 8) atomicAdd(&gu[threadIdx.x], us[threadIdx.x]);
    if (threadIdx.x == 0) atomicAdd(gc, cs);
}

// --- Kernel 3: finalize losses + normalized usage ---
__global__ void router_final(const float* __restrict__ gu, const int* __restrict__ gc,
                             float* __restrict__ out)
{
    if (blockIdx.x == 0 && threadIdx.x == 0) {
        float u[8]; float tot = 0.0f;
        for (int e = 0; e < 8; e++) { u[e] = gu[e]; tot += u[e]; }
        float lb = 0.0f;
        for (int e = 0; e < 8; e++) {
            float un = u[e] / tot;
            out[2 * MTOK * NEXP + 1 + e] = un;
            float d = un - 0.125f;
            lb += d * d;
        }
        lb *= (1.0f / 8.0f);
        float sp = ((float)(*gc) / (float)MTOK) * 0.5f;
        out[2 * MTOK * NEXP] = lb + 0.1f * sp;
    }
}

extern "C" void kernel_launch(void* const* d_in, const int* in_sizes, int n_in,
                              void* d_out, int out_size, void* d_ws, size_t ws_size,
                              hipStream_t stream) {
    const float* x  = (const float*)d_in[0];
    const float* w1 = (const float*)d_in[1];
    const float* b1 = (const float*)d_in[2];
    const float* w2 = (const float*)d_in[3];
    const float* b2 = (const float*)d_in[4];
    float* out = (float*)d_out;

    unsigned short* xh   = (unsigned short*)d_ws;                 // 33.55 MB
    unsigned short* xl   = xh + (size_t)MTOK * HDIM;              // 33.55 MB
    unsigned short* w1th = xl + (size_t)MTOK * HDIM;              // 4 MB
    unsigned short* w1tl = w1th + (size_t)FDIM * HDIM;            // 4 MB
    float* part = (float*)(w1tl + (size_t)FDIM * HDIM);           // 16.78 MB
    float* gu = part + (size_t)NSLC * MTOK * NEXP;
    int* gc = (int*)(gu + 8);

    hipMemsetAsync(gu, 0, 64, stream);

    cvt_x<<<(MTOK * HDIM) / (256 * 8), 256, 0, stream>>>(x, xh, xl);
    cvt_w1t<<<dim3(FDIM / 32, HDIM / 32), 256, 0, stream>>>(w1, w1th, w1tl);
    gemm1_mfma<<<dim3(FDIM / BN, MTOK / BM), 256, 0, stream>>>(
        xh, xl, w1th, w1tl, b1, w2, part);
    router_topk<<<MTOK / 256, 256, 0, stream>>>(part, b2, out, gu, gc);
    router_final<<<1, 64, 0, stream>>>(gu, gc, out);
}

// Round 4
// 363.173 us; speedup vs baseline: 2.5297x; 1.5210x over previous
//
#include <hip/hip_runtime.h>
#include <math.h>

#define HDIM 1024
#define FDIM 2048   // 2H
#define NEXP 8
#define MTOK 16384  // 8*2048 tokens
#define NSLC 32     // partial-logit slices: 16 n-blocks x 2 wn-waves

// Packed split-bf16 layout: per row, 128 k8-groups; group g stores
// [h-chunk (8 bf16, 16B)][l-chunk (16B)] -> row = 2048 shorts = 4 KB.
// One K-iter (BK=32) consumes groups 4t..4t+3 = contiguous 128 B.
#define ROWS 2048   // shorts per packed row

typedef __attribute__((ext_vector_type(8))) short bf16x8;   // 8 bf16 = 4 VGPRs
typedef __attribute__((ext_vector_type(4))) float f32x4;

__device__ inline unsigned short f2bf_rne(float f) {
    unsigned int u = __float_as_uint(f);
    u = (u + 0x7FFFu + ((u >> 16) & 1u)) >> 16;
    return (unsigned short)u;
}
__device__ inline float bf2f(unsigned short h) {
    unsigned int u = ((unsigned int)h) << 16;
    return __uint_as_float(u);
}

// --- Kernel A: x fp32 -> packed (h,l) bf16 split rows ---
__global__ __launch_bounds__(256) void cvt_x(const float* __restrict__ x,
                                             unsigned short* __restrict__ xi)
{
    size_t g = (size_t)blockIdx.x * 256 + threadIdx.x;  // k8-group id
    size_t m = g >> 7, k8 = g & 127;
    const float* p = x + g * 8;
    float v[8];
    *(float4*)(v)     = *(const float4*)(p);
    *(float4*)(v + 4) = *(const float4*)(p + 4);
    union { unsigned short u[8]; uint4 q; } oh, ol;
    #pragma unroll
    for (int j = 0; j < 8; j++) {
        unsigned short h = f2bf_rne(v[j]);
        oh.u[j] = h;
        ol.u[j] = f2bf_rne(v[j] - bf2f(h));
    }
    unsigned short* dst = xi + m * ROWS + k8 * 16;
    *(uint4*)dst = oh.q;
    *(uint4*)(dst + 8) = ol.q;
}

// --- Kernel B: w1 [K][N] fp32 -> transposed packed split rows wi[N] ---
__global__ __launch_bounds__(256) void cvt_w1t(const float* __restrict__ w1,
                                               unsigned short* __restrict__ wi)
{
    __shared__ float t[32][33];
    int n0 = blockIdx.x * 32;   // over FDIM
    int k0 = blockIdx.y * 32;   // over HDIM
    int lx = threadIdx.x & 31, ly = threadIdx.x >> 5;  // 32 x 8
    #pragma unroll
    for (int r = 0; r < 32; r += 8)
        t[ly + r][lx] = w1[(size_t)(k0 + ly + r) * FDIM + n0 + lx];
    __syncthreads();
    #pragma unroll
    for (int r = 0; r < 32; r += 8) {
        float v = t[lx][ly + r];
        unsigned short h = f2bf_rne(v);
        unsigned short l = f2bf_rne(v - bf2f(h));
        int k = k0 + lx;
        size_t o = (size_t)(n0 + ly + r) * ROWS + (size_t)(k >> 3) * 16 + (k & 7);
        wi[o] = h;
        wi[o + 8] = l;
    }
}

// --- Kernel C: split-bf16 MFMA GEMM1, double-buffered LDS, swizzled ---
// C-tile 128x128/block, 4 waves 2x2, each 64x64 via 4x4 frags of 16x16x32.
// Per K-iter: acc += ah*bh + ah*bl + al*bh (xl*wl dropped: 2^-18 rel).
// LDS slot c: m = c>>3, j_slot = c&7, global chunk j = j_slot ^ (m&7).
// Staging: lane-contiguous slots -> permuted-within-128B-line global reads
// (full coalescing). Fragment reads: bank quad = j ^ (m&7) -> 2-way (free).
#define BM 128
#define BN 128

__global__ __launch_bounds__(256, 2) void gemm1_mfma(
    const unsigned short* __restrict__ xi, const unsigned short* __restrict__ wi,
    const float* __restrict__ b1, const float* __restrict__ w2,
    float* __restrict__ part)
{
    __shared__ __align__(16) short As[2][BM * 64];  // 2 x 16 KB
    __shared__ __align__(16) short Bs[2][BN * 64];  // 2 x 16 KB

    const int tid  = threadIdx.x;
    const int lane = tid & 63;
    const int l15  = lane & 15;
    const int q    = lane >> 4;
    const int wave = tid >> 6;
    const int wm   = wave & 1;
    const int wn   = wave >> 1;
    const int bn = blockIdx.x, bm = blockIdx.y;
    const int m0 = bm * BM, n0 = bn * BN;

    // staging base pointers (fixed per thread; advance 64 shorts per iter)
    const unsigned short* ap[4];
    const unsigned short* bp[4];
    #pragma unroll
    for (int s = 0; s < 4; s++) {
        int cc = s * 256 + tid;
        int m = cc >> 3;
        int j = (cc & 7) ^ (m & 7);
        ap[s] = xi + (size_t)(m0 + m) * ROWS + j * 8;
        bp[s] = wi + (size_t)(n0 + m) * ROWS + j * 8;
    }

    // fragment LDS offsets (shorts); [0]=h chunk (j=2q), [1]=l chunk (j=2q+1)
    int offA[2][4], offB[2][4];
    #pragma unroll
    for (int i = 0; i < 4; i++) {
        int ma = wm * 64 + i * 16 + l15;
        offA[0][i] = (ma * 8 + ((2 * q)     ^ (ma & 7))) * 8;
        offA[1][i] = (ma * 8 + ((2 * q + 1) ^ (ma & 7))) * 8;
        int nb = wn * 64 + i * 16 + l15;
        offB[0][i] = (nb * 8 + ((2 * q)     ^ (nb & 7))) * 8;
        offB[1][i] = (nb * 8 + ((2 * q + 1) ^ (nb & 7))) * 8;
    }

    f32x4 acc[4][4];
    #pragma unroll
    for (int i = 0; i < 4; i++)
        #pragma unroll
        for (int j = 0; j < 4; j++) acc[i][j] = (f32x4){0.f, 0.f, 0.f, 0.f};

    // prologue: stage iter 0 into buf 0
    #pragma unroll
    for (int s = 0; s < 4; s++) {
        int lo = (s * 256 + tid) * 8;
        __builtin_amdgcn_global_load_lds(
            (const __attribute__((address_space(1))) void*)(ap[s]),
            (__attribute__((address_space(3))) void*)&As[0][lo], 16, 0, 0);
        __builtin_amdgcn_global_load_lds(
            (const __attribute__((address_space(1))) void*)(bp[s]),
            (__attribute__((address_space(3))) void*)&Bs[0][lo], 16, 0, 0);
    }

    for (int t = 0; t < 32; t++) {
        __syncthreads();  // vmcnt drain: buf[t&1] staged; prev reads done
        if (t + 1 < 32) {
            const int nbuf = (t + 1) & 1;
            #pragma unroll
            for (int s = 0; s < 4; s++) {
                int lo = (s * 256 + tid) * 8;
                __builtin_amdgcn_global_load_lds(
                    (const __attribute__((address_space(1))) void*)(ap[s] + (t + 1) * 64),
                    (__attribute__((address_space(3))) void*)&As[nbuf][lo], 16, 0, 0);
                __builtin_amdgcn_global_load_lds(
                    (const __attribute__((address_space(1))) void*)(bp[s] + (t + 1) * 64),
                    (__attribute__((address_space(3))) void*)&Bs[nbuf][lo], 16, 0, 0);
            }
        }
        const short* a = As[t & 1];
        const short* b = Bs[t & 1];

        bf16x8 ah[4], al[4], bh[4], bl[4];
        #pragma unroll
        for (int i = 0; i < 4; i++) {
            ah[i] = *(const bf16x8*)&a[offA[0][i]];
            al[i] = *(const bf16x8*)&a[offA[1][i]];
            bh[i] = *(const bf16x8*)&b[offB[0][i]];
            bl[i] = *(const bf16x8*)&b[offB[1][i]];
        }
        #pragma unroll
        for (int i = 0; i < 4; i++)
            #pragma unroll
            for (int j = 0; j < 4; j++) {
                acc[i][j] = __builtin_amdgcn_mfma_f32_16x16x32_bf16(
                    ah[i], bh[j], acc[i][j], 0, 0, 0);
                acc[i][j] = __builtin_amdgcn_mfma_f32_16x16x32_bf16(
                    ah[i], bl[j], acc[i][j], 0, 0, 0);
                acc[i][j] = __builtin_amdgcn_mfma_f32_16x16x32_bf16(
                    al[i], bh[j], acc[i][j], 0, 0, 0);
            }
    }

    // --- epilogue: bias + exact GELU (C/D: col=lane&15 -> n, row=q*4+r -> m) ---
    #pragma unroll
    for (int j = 0; j < 4; j++) {
        int n = n0 + wn * 64 + j * 16 + l15;
        float bb = b1[n];
        #pragma unroll
        for (int i = 0; i < 4; i++)
            #pragma unroll
            for (int r = 0; r < 4; r++) {
                float v = acc[i][j][r] + bb;
                acc[i][j][r] = 0.5f * v * (1.0f + erff(v * 0.70710678118654752f));
            }
    }

    // w2 rows for this lane's 4 n-columns
    float w2r[4][8];
    #pragma unroll
    for (int j = 0; j < 4; j++) {
        const float4* p = (const float4*)(w2 + (size_t)(n0 + wn * 64 + j * 16 + l15) * NEXP);
        float4 u = p[0], v = p[1];
        w2r[j][0] = u.x; w2r[j][1] = u.y; w2r[j][2] = u.z; w2r[j][3] = u.w;
        w2r[j][4] = v.x; w2r[j][5] = v.y; w2r[j][6] = v.z; w2r[j][7] = v.w;
    }

    const int sl = bn * 2 + wn;  // partial slice (deterministic)
    #pragma unroll
    for (int e = 0; e < NEXP; e++) {
        float p[4][4];
        #pragma unroll
        for (int i = 0; i < 4; i++)
            #pragma unroll
            for (int r = 0; r < 4; r++) {
                float s = 0.f;
                #pragma unroll
                for (int j = 0; j < 4; j++) s += acc[i][j][r] * w2r[j][e];
                p[i][r] = s;
            }
        #pragma unroll
        for (int off = 1; off < 16; off <<= 1)
            #pragma unroll
            for (int i = 0; i < 4; i++)
                #pragma unroll
                for (int r = 0; r < 4; r++)
                    p[i][r] += __shfl_xor(p[i][r], off);
        if (l15 == 0) {
            #pragma unroll
            for (int i = 0; i < 4; i++)
                #pragma unroll
                for (int r = 0; r < 4; r++) {
                    int m = m0 + wm * 64 + i * 16 + q * 4 + r;
                    part[(size_t)sl * (MTOK * NEXP) + (size_t)m * NEXP + e] = p[i][r];
                }
        }
    }
}

// --- Kernel 2: deterministic sum of 32 slices -> logits, top-2, softmax ---
__global__ __launch_bounds__(256) void router_topk(
    const float* __restrict__ part, const float* __restrict__ b2,
    float* __restrict__ out, float* __restrict__ gu, int* __restrict__ gc)
{
    const int t = blockIdx.x * 256 + threadIdx.x;

    float logit[8];
    #pragma unroll
    for (int e = 0; e < 8; e++) logit[e] = b2[e];
    #pragma unroll
    for (int j = 0; j < NSLC; j++) {
        const float4* p4 = (const float4*)(part + (size_t)j * (MTOK * NEXP) + (size_t)t * NEXP);
        float4 u = p4[0], v = p4[1];
        logit[0] += u.x; logit[1] += u.y; logit[2] += u.z; logit[3] += u.w;
        logit[4] += v.x; logit[5] += v.y; logit[6] += v.z; logit[7] += v.w;
    }

    int i1 = 0; float v1 = logit[0];
    #pragma unroll
    for (int e = 1; e < 8; e++) { if (logit[e] > v1) { v1 = logit[e]; i1 = e; } }
    int i2 = -1; float v2 = -INFINITY;
    #pragma unroll
    for (int e = 0; e < 8; e++) {
        if (e != i1 && logit[e] > v2) { v2 = logit[e]; i2 = e; }
    }
    float ex = expf(v2 - v1);
    float inv = 1.0f / (1.0f + ex);
    float wa = inv, wb = ex * inv;

    float4* o = (float4*)(out + (size_t)t * NEXP);
    o[0] = make_float4(logit[0], logit[1], logit[2], logit[3]);
    o[1] = make_float4(logit[4], logit[5], logit[6], logit[7]);

    float mk[8];
    #pragma unroll
    for (int e = 0; e < 8; e++) mk[e] = 0.0f;
    mk[i1] = wa; mk[i2] = wb;
    float4* om = (float4*)(out + (size_t)(MTOK * NEXP) + (size_t)t * NEXP);
    om[0] = make_float4(mk[0], mk[1], mk[2], mk[3]);
    om[1] = make_float4(mk[4], mk[5], mk[6], mk[7]);

    __shared__ float us[8];
    __shared__ int cs;
    if (threadIdx.x < 8) us[threadIdx.x] = 0.0f;
    if (threadIdx.x == 0) cs = 0;
    __syncthreads();
    atomicAdd(&us[i1], wa);
    atomicAdd(&us[i2], wb);
    int cnt = (wa > 0.0f ? 1 : 0) + (wb > 0.0f ? 1 : 0);
    atomicAdd(&cs, cnt);
    __syncthreads();
    if (threadIdx.x < 8) atomicAdd(&gu[threadIdx.x], us[threadIdx.x]);
    if (threadIdx.x == 0) atomicAdd(gc, cs);
}

// --- Kernel 3: finalize losses + normalized usage ---
__global__ void router_final(const float* __restrict__ gu, const int* __restrict__ gc,
                             float* __restrict__ out)
{
    if (blockIdx.x == 0 && threadIdx.x == 0) {
        float u[8]; float tot = 0.0f;
        for (int e = 0; e < 8; e++) { u[e] = gu[e]; tot += u[e]; }
        float lb = 0.0f;
        for (int e = 0; e < 8; e++) {
            float un = u[e] / tot;
            out[2 * MTOK * NEXP + 1 + e] = un;
            float d = un - 0.125f;
            lb += d * d;
        }
        lb *= (1.0f / 8.0f);
        float sp = ((float)(*gc) / (float)MTOK) * 0.5f;
        out[2 * MTOK * NEXP] = lb + 0.1f * sp;
    }
}

extern "C" void kernel_launch(void* const* d_in, const int* in_sizes, int n_in,
                              void* d_out, int out_size, void* d_ws, size_t ws_size,
                              hipStream_t stream) {
    const float* x  = (const float*)d_in[0];
    const float* w1 = (const float*)d_in[1];
    const float* b1 = (const float*)d_in[2];
    const float* w2 = (const float*)d_in[3];
    const float* b2 = (const float*)d_in[4];
    float* out = (float*)d_out;

    unsigned short* xi = (unsigned short*)d_ws;            // 16384*2048*2 = 64 MB
    unsigned short* wi = xi + (size_t)MTOK * ROWS;         // 2048*2048*2  =  8 MB
    float* part = (float*)(wi + (size_t)FDIM * ROWS);      // 16.78 MB
    float* gu = part + (size_t)NSLC * MTOK * NEXP;
    int* gc = (int*)(gu + 8);

    hipMemsetAsync(gu, 0, 64, stream);

    cvt_x<<<(MTOK * HDIM / 8) / 256, 256, 0, stream>>>(x, xi);
    cvt_w1t<<<dim3(FDIM / 32, HDIM / 32), 256, 0, stream>>>(w1, wi);
    gemm1_mfma<<<dim3(FDIM / BN, MTOK / BM), 256, 0, stream>>>(xi, wi, b1, w2, part);
    router_topk<<<MTOK / 256, 256, 0, stream>>>(part, b2, out, gu, gc);
    router_final<<<1, 64, 0, stream>>>(gu, gc, out);
}

// Round 5
// 351.601 us; speedup vs baseline: 2.6129x; 1.0329x over previous
//
#include <hip/hip_runtime.h>
#include <math.h>

#define HDIM 1024
#define FDIM 2048   // 2H
#define NEXP 8
#define MTOK 16384  // 8*2048 tokens
#define NSLC 32     // partial-logit slices: 16 n-blocks x 2 wn-waves
#define ROWS 2048   // shorts per packed A row ([h8|l8] per k8-group)
#define BM 128
#define BN 128

typedef __attribute__((ext_vector_type(8))) short bf16x8;   // 8 bf16 = 4 VGPRs
typedef __attribute__((ext_vector_type(4))) float f32x4;

__device__ inline unsigned short f2bf_rne(float f) {
    unsigned int u = __float_as_uint(f);
    u = (u + 0x7FFFu + ((u >> 16) & 1u)) >> 16;
    return (unsigned short)u;
}
__device__ inline float bf2f(unsigned short h) {
    unsigned int u = ((unsigned int)h) << 16;
    return __uint_as_float(u);
}

// --- Kernel A: x fp32 -> packed (h,l) bf16 split rows (for LDS staging) ---
__global__ __launch_bounds__(256) void cvt_x(const float* __restrict__ x,
                                             unsigned short* __restrict__ xi)
{
    size_t g = (size_t)blockIdx.x * 256 + threadIdx.x;  // k8-group id
    size_t m = g >> 7, k8 = g & 127;
    const float* p = x + g * 8;
    float v[8];
    *(float4*)(v)     = *(const float4*)(p);
    *(float4*)(v + 4) = *(const float4*)(p + 4);
    union { unsigned short u[8]; uint4 q; } oh, ol;
    #pragma unroll
    for (int j = 0; j < 8; j++) {
        unsigned short h = f2bf_rne(v[j]);
        oh.u[j] = h;
        ol.u[j] = f2bf_rne(v[j] - bf2f(h));
    }
    unsigned short* dst = xi + m * ROWS + k8 * 16;
    *(uint4*)dst = oh.q;
    *(uint4*)(dst + 8) = ol.q;
}

// --- Kernel B: w1 [K][N] fp32 -> FRAGMENT-MAJOR split bf16 wf ---
// wf[nt][kb][hl][lane][j]: nt=n>>4 (128), kb=k>>5 (32), hl in {h,l},
// lane = ((k>>3)&3)*16 + (n&15), j = k&7.  A wave's B-fragment load is
// base + lane*16B: one coalesced 1 KB global_load_dwordx4, no LDS needed.
__global__ __launch_bounds__(256) void cvt_w1f(const float* __restrict__ w1,
                                               unsigned short* __restrict__ wf)
{
    __shared__ float t[32][33];
    int n0 = blockIdx.x * 32;   // over FDIM
    int k0 = blockIdx.y * 32;   // over HDIM
    int lx = threadIdx.x & 31, ly = threadIdx.x >> 5;  // 32 x 8
    #pragma unroll
    for (int r = 0; r < 32; r += 8)
        t[ly + r][lx] = w1[(size_t)(k0 + ly + r) * FDIM + n0 + lx];
    __syncthreads();
    #pragma unroll
    for (int r = 0; r < 32; r += 8) {
        float v = t[lx][ly + r];
        unsigned short h = f2bf_rne(v);
        unsigned short l = f2bf_rne(v - bf2f(h));
        int n = n0 + ly + r, k = k0 + lx;
        size_t base = (size_t)((n >> 4) * 32 + (k >> 5)) * 1024;  // 2*512
        int lj = (((k >> 3) & 3) * 16 + (n & 15)) * 8 + (k & 7);
        wf[base + lj] = h;
        wf[base + 512 + lj] = l;
    }
}

// --- Kernel C: split-bf16 MFMA GEMM1. A via dbuf LDS; B direct from L2. ---
// C-tile 128x128/block, 4 waves 2x2, each 64x64 via 4x4 frags of 16x16x32.
// Per K-iter (BK=32): acc += ah*bh + ah*bl + al*bh (xl*wl dropped: 2^-18).
__global__ __launch_bounds__(256, 2) void gemm1_mfma(
    const unsigned short* __restrict__ xi, const unsigned short* __restrict__ wf,
    const float* __restrict__ b1, const float* __restrict__ w2,
    float* __restrict__ part)
{
    __shared__ __align__(16) short As[2][BM * 64];  // 2 x 16 KB

    const int tid  = threadIdx.x;
    const int lane = tid & 63;
    const int l15  = lane & 15;
    const int q    = lane >> 4;
    const int wave = tid >> 6;
    const int wm   = wave & 1;
    const int wn   = wave >> 1;
    const int bm = blockIdx.x, bn = blockIdx.y;  // bm-major dispatch: resident
    const int m0 = bm * BM, n0 = bn * BN;        // blocks share bn -> B hot in L2

    // A staging pointers (lane-contiguous LDS slots; XOR-permuted global chunks
    // within each row's 128 B segment -> still full-line coalesced)
    const unsigned short* ap[4];
    #pragma unroll
    for (int s = 0; s < 4; s++) {
        int c = s * 256 + tid;
        int m = c >> 3;
        int g = (c & 7) ^ (m & 7);
        ap[s] = xi + (size_t)(m0 + m) * ROWS + g * 8;
    }

    // B fragment pointers (fragment-major: base + lane*16B)
    const unsigned short* bq[4][2];
    #pragma unroll
    for (int f = 0; f < 4; f++) {
        int nt = bn * 8 + wn * 4 + f;
        #pragma unroll
        for (int h = 0; h < 2; h++)
            bq[f][h] = wf + (size_t)nt * 32768 + h * 512 + lane * 8;
    }

    // A fragment LDS offsets (shorts); bank quad = chunk^(m&7) -> 2-way (free)
    int offA[2][4];
    #pragma unroll
    for (int i = 0; i < 4; i++) {
        int ma = wm * 64 + i * 16 + l15;
        offA[0][i] = (ma * 8 + ((2 * q)     ^ (ma & 7))) * 8;
        offA[1][i] = (ma * 8 + ((2 * q + 1) ^ (ma & 7))) * 8;
    }

    f32x4 acc[4][4];
    #pragma unroll
    for (int i = 0; i < 4; i++)
        #pragma unroll
        for (int j = 0; j < 4; j++) acc[i][j] = (f32x4){0.f, 0.f, 0.f, 0.f};

    // prologue: stage A iter 0 into buf 0
    #pragma unroll
    for (int s = 0; s < 4; s++)
        __builtin_amdgcn_global_load_lds(
            (const __attribute__((address_space(1))) void*)(ap[s]),
            (__attribute__((address_space(3))) void*)&As[0][(s * 256 + tid) * 8],
            16, 0, 0);

    for (int t = 0; t < 32; t++) {
        __syncthreads();  // A[t] staged (vmcnt drain)

        // B loads for this iter first (L1/L2-hit; latency overlapped by TLP)
        bf16x8 bh[4], bl[4];
        #pragma unroll
        for (int f = 0; f < 4; f++) {
            bh[f] = *(const bf16x8*)(bq[f][0] + t * 1024);
            bl[f] = *(const bf16x8*)(bq[f][1] + t * 1024);
        }
        // prefetch-stage A[t+1] into the other buffer
        if (t + 1 < 32) {
            const int nbuf = (t + 1) & 1;
            #pragma unroll
            for (int s = 0; s < 4; s++)
                __builtin_amdgcn_global_load_lds(
                    (const __attribute__((address_space(1))) void*)(ap[s] + (t + 1) * 64),
                    (__attribute__((address_space(3))) void*)&As[nbuf][(s * 256 + tid) * 8],
                    16, 0, 0);
        }

        const short* a = As[t & 1];
        bf16x8 ah[4], al[4];
        #pragma unroll
        for (int i = 0; i < 4; i++) {
            ah[i] = *(const bf16x8*)&a[offA[0][i]];
            al[i] = *(const bf16x8*)&a[offA[1][i]];
        }
        #pragma unroll
        for (int i = 0; i < 4; i++)
            #pragma unroll
            for (int j = 0; j < 4; j++) {
                acc[i][j] = __builtin_amdgcn_mfma_f32_16x16x32_bf16(
                    ah[i], bh[j], acc[i][j], 0, 0, 0);
                acc[i][j] = __builtin_amdgcn_mfma_f32_16x16x32_bf16(
                    ah[i], bl[j], acc[i][j], 0, 0, 0);
                acc[i][j] = __builtin_amdgcn_mfma_f32_16x16x32_bf16(
                    al[i], bh[j], acc[i][j], 0, 0, 0);
            }
    }

    // --- epilogue: bias + exact GELU (C/D: col=lane&15 -> n, row=q*4+r -> m) ---
    #pragma unroll
    for (int j = 0; j < 4; j++) {
        int n = n0 + wn * 64 + j * 16 + l15;
        float bb = b1[n];
        #pragma unroll
        for (int i = 0; i < 4; i++)
            #pragma unroll
            for (int r = 0; r < 4; r++) {
                float v = acc[i][j][r] + bb;
                acc[i][j][r] = 0.5f * v * (1.0f + erff(v * 0.70710678118654752f));
            }
    }

    // w2 rows for this lane's 4 n-columns
    float w2r[4][8];
    #pragma unroll
    for (int j = 0; j < 4; j++) {
        const float4* p = (const float4*)(w2 + (size_t)(n0 + wn * 64 + j * 16 + l15) * NEXP);
        float4 u = p[0], v = p[1];
        w2r[j][0] = u.x; w2r[j][1] = u.y; w2r[j][2] = u.z; w2r[j][3] = u.w;
        w2r[j][4] = v.x; w2r[j][5] = v.y; w2r[j][6] = v.z; w2r[j][7] = v.w;
    }

    const int sl = bn * 2 + wn;  // partial slice (deterministic)
    #pragma unroll
    for (int e = 0; e < NEXP; e++) {
        float p[4][4];
        #pragma unroll
        for (int i = 0; i < 4; i++)
            #pragma unroll
            for (int r = 0; r < 4; r++) {
                float s = 0.f;
                #pragma unroll
                for (int j = 0; j < 4; j++) s += acc[i][j][r] * w2r[j][e];
                p[i][r] = s;
            }
        #pragma unroll
        for (int off = 1; off < 16; off <<= 1)
            #pragma unroll
            for (int i = 0; i < 4; i++)
                #pragma unroll
                for (int r = 0; r < 4; r++)
                    p[i][r] += __shfl_xor(p[i][r], off);
        if (l15 == 0) {
            #pragma unroll
            for (int i = 0; i < 4; i++)
                #pragma unroll
                for (int r = 0; r < 4; r++) {
                    int m = m0 + wm * 64 + i * 16 + q * 4 + r;
                    part[(size_t)sl * (MTOK * NEXP) + (size_t)m * NEXP + e] = p[i][r];
                }
        }
    }
}

// --- Kernel 2: deterministic sum of 32 slices -> logits, top-2, softmax ---
__global__ __launch_bounds__(256) void router_topk(
    const float* __restrict__ part, const float* __restrict__ b2,
    float* __restrict__ out, float* __restrict__ gu, int* __restrict__ gc)
{
    const int t = blockIdx.x * 256 + threadIdx.x;

    float logit[8];
    #pragma unroll
    for (int e = 0; e < 8; e++) logit[e] = b2[e];
    #pragma unroll
    for (int j = 0; j < NSLC; j++) {
        const float4* p4 = (const float4*)(part + (size_t)j * (MTOK * NEXP) + (size_t)t * NEXP);
        float4 u = p4[0], v = p4[1];
        logit[0] += u.x; logit[1] += u.y; logit[2] += u.z; logit[3] += u.w;
        logit[4] += v.x; logit[5] += v.y; logit[6] += v.z; logit[7] += v.w;
    }

    int i1 = 0; float v1 = logit[0];
    #pragma unroll
    for (int e = 1; e < 8; e++) { if (logit[e] > v1) { v1 = logit[e]; i1 = e; } }
    int i2 = -1; float v2 = -INFINITY;
    #pragma unroll
    for (int e = 0; e < 8; e++) {
        if (e != i1 && logit[e] > v2) { v2 = logit[e]; i2 = e; }
    }
    float ex = expf(v2 - v1);
    float inv = 1.0f / (1.0f + ex);
    float wa = inv, wb = ex * inv;

    float4* o = (float4*)(out + (size_t)t * NEXP);
    o[0] = make_float4(logit[0], logit[1], logit[2], logit[3]);
    o[1] = make_float4(logit[4], logit[5], logit[6], logit[7]);

    float mk[8];
    #pragma unroll
    for (int e = 0; e < 8; e++) mk[e] = 0.0f;
    mk[i1] = wa; mk[i2] = wb;
    float4* om = (float4*)(out + (size_t)(MTOK * NEXP) + (size_t)t * NEXP);
    om[0] = make_float4(mk[0], mk[1], mk[2], mk[3]);
    om[1] = make_float4(mk[4], mk[5], mk[6], mk[7]);

    __shared__ float us[8];
    __shared__ int cs;
    if (threadIdx.x < 8) us[threadIdx.x] = 0.0f;
    if (threadIdx.x == 0) cs = 0;
    __syncthreads();
    atomicAdd(&us[i1], wa);
    atomicAdd(&us[i2], wb);
    int cnt = (wa > 0.0f ? 1 : 0) + (wb > 0.0f ? 1 : 0);
    atomicAdd(&cs, cnt);
    __syncthreads();
    if (threadIdx.x < 8) atomicAdd(&gu[threadIdx.x], us[threadIdx.x]);
    if (threadIdx.x == 0) atomicAdd(gc, cs);
}

// --- Kernel 3: finalize losses + normalized usage ---
__global__ void router_final(const float* __restrict__ gu, const int* __restrict__ gc,
                             float* __restrict__ out)
{
    if (blockIdx.x == 0 && threadIdx.x == 0) {
        float u[8]; float tot = 0.0f;
        for (int e = 0; e < 8; e++) { u[e] = gu[e]; tot += u[e]; }
        float lb = 0.0f;
        for (int e = 0; e < 8; e++) {
            float un = u[e] / tot;
            out[2 * MTOK * NEXP + 1 + e] = un;
            float d = un - 0.125f;
            lb += d * d;
        }
        lb *= (1.0f / 8.0f);
        float sp = ((float)(*gc) / (float)MTOK) * 0.5f;
        out[2 * MTOK * NEXP] = lb + 0.1f * sp;
    }
}

extern "C" void kernel_launch(void* const* d_in, const int* in_sizes, int n_in,
                              void* d_out, int out_size, void* d_ws, size_t ws_size,
                              hipStream_t stream) {
    const float* x  = (const float*)d_in[0];
    const float* w1 = (const float*)d_in[1];
    const float* b1 = (const float*)d_in[2];
    const float* w2 = (const float*)d_in[3];
    const float* b2 = (const float*)d_in[4];
    float* out = (float*)d_out;

    unsigned short* xi = (unsigned short*)d_ws;            // 16384*2048*2 B = 64 MiB
    unsigned short* wf = xi + (size_t)MTOK * ROWS;         // 128*32*1024*2 B = 8 MiB
    float* part = (float*)(wf + (size_t)128 * 32 * 1024);  // 16 MiB
    float* gu = part + (size_t)NSLC * MTOK * NEXP;
    int* gc = (int*)(gu + 8);

    hipMemsetAsync(gu, 0, 64, stream);

    cvt_x<<<(MTOK * HDIM / 8) / 256, 256, 0, stream>>>(x, xi);
    cvt_w1f<<<dim3(FDIM / 32, HDIM / 32), 256, 0, stream>>>(w1, wf);
    gemm1_mfma<<<dim3(MTOK / BM, FDIM / BN), 256, 0, stream>>>(xi, wf, b1, w2, part);
    router_topk<<<MTOK / 256, 256, 0, stream>>>(part, b2, out, gu, gc);
    router_final<<<1, 64, 0, stream>>>(gu, gc, out);
}

// Round 6
// 345.786 us; speedup vs baseline: 2.6569x; 1.0168x over previous
//
#include <hip/hip_runtime.h>
#include <math.h>

#define HDIM 1024
#define FDIM 2048   // 2H
#define NEXP 8
#define MTOK 16384  // 8*2048 tokens
#define NSLC 32     // partial-logit slices: 16 n-blocks x 2 wn-waves
#define BM 128
#define BN 128

typedef __attribute__((ext_vector_type(8))) short bf16x8;   // 8 bf16 = 4 VGPRs
typedef __attribute__((ext_vector_type(4))) float f32x4;

__device__ inline unsigned short f2bf_rne(float f) {
    unsigned int u = __float_as_uint(f);
    u = (u + 0x7FFFu + ((u >> 16) & 1u)) >> 16;
    return (unsigned short)u;
}
__device__ inline float bf2f(unsigned short h) {
    unsigned int u = ((unsigned int)h) << 16;
    return __uint_as_float(u);
}

// --- Kernel A: x fp32 -> FRAGMENT-MAJOR split bf16 af ---
// af[mt][kb][hl][lane][j]: mt=m>>4 (1024), kb=k>>5 (32), hl in {h,l},
// lane = ((k>>3)&3)*16 + (m&15), j = k&7. Per (mt,kb): 1024 shorts (2 KB).
// A wave's A-fragment load in the GEMM = base + lane*16B (coalesced 1 KB).
// LDS transpose ([kb][m][q][j] staging) keeps both phases coalesced and
// bank-conflict-free (64 distinct (m,q) quad-offsets cover banks uniformly).
__global__ __launch_bounds__(256) void cvt_x(const float* __restrict__ x,
                                             unsigned short* __restrict__ af)
{
    __shared__ unsigned short hs[16384];  // 32 KB  [kb][m][q][j]
    __shared__ unsigned short ls[16384];  // 32 KB
    const int mt = blockIdx.x;            // 0..1023
    const float* src = x + (size_t)mt * 16384;
    const int m = threadIdx.x & 15;
    const int kseg = threadIdx.x >> 4;    // 0..15

    #pragma unroll
    for (int c = 0; c < 8; c++) {
        int k = c * 128 + kseg * 8;
        float v[8];
        *(float4*)(v)     = *(const float4*)(src + m * 1024 + k);
        *(float4*)(v + 4) = *(const float4*)(src + m * 1024 + k + 4);
        union { unsigned short u[8]; uint4 q; } oh, ol;
        #pragma unroll
        for (int j = 0; j < 8; j++) {
            unsigned short h = f2bf_rne(v[j]);
            oh.u[j] = h;
            ol.u[j] = f2bf_rne(v[j] - bf2f(h));
        }
        int kb = k >> 5, q = (k >> 3) & 3;
        int o = kb * 512 + m * 32 + q * 8;
        *(uint4*)(hs + o) = oh.q;
        *(uint4*)(ls + o) = ol.q;
    }
    __syncthreads();
    unsigned short* dst = af + (size_t)mt * 32768;
    #pragma unroll
    for (int c = 0; c < 16; c++) {
        int f = c * 2048 + threadIdx.x * 8;       // flat out index (shorts)
        int kb = f >> 10, half = (f >> 9) & 1, idx = f & 511;
        int q = idx >> 7, mm = (idx >> 3) & 15;
        const unsigned short* s = (half ? ls : hs) + kb * 512 + mm * 32 + q * 8;
        *(uint4*)(dst + f) = *(const uint4*)s;
    }
}

// --- Kernel B: w1 [K][N] fp32 -> FRAGMENT-MAJOR split bf16 wf (as round 5) ---
__global__ __launch_bounds__(256) void cvt_w1f(const float* __restrict__ w1,
                                               unsigned short* __restrict__ wf)
{
    __shared__ float t[32][33];
    int n0 = blockIdx.x * 32;   // over FDIM
    int k0 = blockIdx.y * 32;   // over HDIM
    int lx = threadIdx.x & 31, ly = threadIdx.x >> 5;  // 32 x 8
    #pragma unroll
    for (int r = 0; r < 32; r += 8)
        t[ly + r][lx] = w1[(size_t)(k0 + ly + r) * FDIM + n0 + lx];
    __syncthreads();
    #pragma unroll
    for (int r = 0; r < 32; r += 8) {
        float v = t[lx][ly + r];
        unsigned short h = f2bf_rne(v);
        unsigned short l = f2bf_rne(v - bf2f(h));
        int n = n0 + ly + r, k = k0 + lx;
        size_t base = (size_t)((n >> 4) * 32 + (k >> 5)) * 1024;
        int lj = (((k >> 3) & 3) * 16 + (n & 15)) * 8 + (k & 7);
        wf[base + lj] = h;
        wf[base + 512 + lj] = l;
    }
}

// --- Kernel C: split-bf16 MFMA GEMM1 — NO LDS, NO BARRIERS in K-loop. ---
// Both operands fragment-major in global (L1/L2-hit); register double-buffer
// one kb ahead -> compiler emits fine-grained vmcnt, MFMA/load interleave.
// 4 waves, 2x2 of 64x64 tiles; acc += ah*bh + ah*bl + al*bh per kb.
__global__ __launch_bounds__(256, 2) void gemm1_mfma(
    const unsigned short* __restrict__ af, const unsigned short* __restrict__ wf,
    const float* __restrict__ b1, const float* __restrict__ w2,
    float* __restrict__ part)
{
    const int tid  = threadIdx.x;
    const int lane = tid & 63;
    const int l15  = lane & 15;
    const int q    = lane >> 4;
    const int wave = tid >> 6;
    const int wm   = wave & 1;
    const int wn   = wave >> 1;

    // XCD-aware swizzle: same-XCD sequences walk 4-bm strips x 16 bn so each
    // XCD's L2 holds its A strip (~2 MB) + current B tile; A read once/XCD.
    const int id = blockIdx.x;          // 0..2047 linear
    const int xcd = id & 7, seq = id >> 3;
    const int strip = seq >> 6;         // 0..3
    const int bn = (seq >> 2) & 15;
    const int bmo = seq & 3;
    const int bm = strip * 32 + xcd * 4 + bmo;
    const int m0 = bm * BM, n0 = bn * BN;

    // fragment pointers: frag i -> mt/nt tile, lane offset fixed
    const unsigned short* apt[4];
    const unsigned short* bpt[4];
    #pragma unroll
    for (int i = 0; i < 4; i++) {
        apt[i] = af + ((size_t)(bm * 8 + wm * 4 + i) * 32) * 1024 + lane * 8;
        bpt[i] = wf + ((size_t)(bn * 8 + wn * 4 + i) * 32) * 1024 + lane * 8;
    }

    f32x4 acc[4][4];
    #pragma unroll
    for (int i = 0; i < 4; i++)
        #pragma unroll
        for (int j = 0; j < 4; j++) acc[i][j] = (f32x4){0.f, 0.f, 0.f, 0.f};

    bf16x8 Ah0[4], Al0[4], Bh0[4], Bl0[4];
    bf16x8 Ah1[4], Al1[4], Bh1[4], Bl1[4];

    // kb = 0 into buf0
    #pragma unroll
    for (int i = 0; i < 4; i++) {
        Ah0[i] = *(const bf16x8*)(apt[i]);
        Al0[i] = *(const bf16x8*)(apt[i] + 512);
        Bh0[i] = *(const bf16x8*)(bpt[i]);
        Bl0[i] = *(const bf16x8*)(bpt[i] + 512);
    }

    #pragma unroll 1
    for (int t = 0; t < 32; t += 2) {
        // prefetch kb = t+1 into buf1 (window offset 1024 shorts)
        #pragma unroll
        for (int i = 0; i < 4; i++) {
            Ah1[i] = *(const bf16x8*)(apt[i] + 1024);
            Al1[i] = *(const bf16x8*)(apt[i] + 1536);
            Bh1[i] = *(const bf16x8*)(bpt[i] + 1024);
            Bl1[i] = *(const bf16x8*)(bpt[i] + 1536);
        }
        // compute kb = t on buf0
        #pragma unroll
        for (int i = 0; i < 4; i++)
            #pragma unroll
            for (int j = 0; j < 4; j++) {
                acc[i][j] = __builtin_amdgcn_mfma_f32_16x16x32_bf16(
                    Ah0[i], Bh0[j], acc[i][j], 0, 0, 0);
                acc[i][j] = __builtin_amdgcn_mfma_f32_16x16x32_bf16(
                    Ah0[i], Bl0[j], acc[i][j], 0, 0, 0);
                acc[i][j] = __builtin_amdgcn_mfma_f32_16x16x32_bf16(
                    Al0[i], Bh0[j], acc[i][j], 0, 0, 0);
            }
        // advance to next window, prefetch kb = t+2 into buf0
        #pragma unroll
        for (int i = 0; i < 4; i++) { apt[i] += 2048; bpt[i] += 2048; }
        if (t + 2 < 32) {
            #pragma unroll
            for (int i = 0; i < 4; i++) {
                Ah0[i] = *(const bf16x8*)(apt[i]);
                Al0[i] = *(const bf16x8*)(apt[i] + 512);
                Bh0[i] = *(const bf16x8*)(bpt[i]);
                Bl0[i] = *(const bf16x8*)(bpt[i] + 512);
            }
        }
        // compute kb = t+1 on buf1
        #pragma unroll
        for (int i = 0; i < 4; i++)
            #pragma unroll
            for (int j = 0; j < 4; j++) {
                acc[i][j] = __builtin_amdgcn_mfma_f32_16x16x32_bf16(
                    Ah1[i], Bh1[j], acc[i][j], 0, 0, 0);
                acc[i][j] = __builtin_amdgcn_mfma_f32_16x16x32_bf16(
                    Ah1[i], Bl1[j], acc[i][j], 0, 0, 0);
                acc[i][j] = __builtin_amdgcn_mfma_f32_16x16x32_bf16(
                    Al1[i], Bh1[j], acc[i][j], 0, 0, 0);
            }
    }

    // --- epilogue: bias + exact GELU (C/D: col=lane&15 -> n, row=q*4+r -> m) ---
    #pragma unroll
    for (int j = 0; j < 4; j++) {
        int n = n0 + wn * 64 + j * 16 + l15;
        float bb = b1[n];
        #pragma unroll
        for (int i = 0; i < 4; i++)
            #pragma unroll
            for (int r = 0; r < 4; r++) {
                float v = acc[i][j][r] + bb;
                acc[i][j][r] = 0.5f * v * (1.0f + erff(v * 0.70710678118654752f));
            }
    }

    // w2 rows for this lane's 4 n-columns
    float w2r[4][8];
    #pragma unroll
    for (int j = 0; j < 4; j++) {
        const float4* p = (const float4*)(w2 + (size_t)(n0 + wn * 64 + j * 16 + l15) * NEXP);
        float4 u = p[0], v = p[1];
        w2r[j][0] = u.x; w2r[j][1] = u.y; w2r[j][2] = u.z; w2r[j][3] = u.w;
        w2r[j][4] = v.x; w2r[j][5] = v.y; w2r[j][6] = v.z; w2r[j][7] = v.w;
    }

    const int sl = bn * 2 + wn;  // partial slice (deterministic)
    #pragma unroll
    for (int e = 0; e < NEXP; e++) {
        float p[4][4];
        #pragma unroll
        for (int i = 0; i < 4; i++)
            #pragma unroll
            for (int r = 0; r < 4; r++) {
                float s = 0.f;
                #pragma unroll
                for (int j = 0; j < 4; j++) s += acc[i][j][r] * w2r[j][e];
                p[i][r] = s;
            }
        #pragma unroll
        for (int off = 1; off < 16; off <<= 1)
            #pragma unroll
            for (int i = 0; i < 4; i++)
                #pragma unroll
                for (int r = 0; r < 4; r++)
                    p[i][r] += __shfl_xor(p[i][r], off);
        if (l15 == 0) {
            #pragma unroll
            for (int i = 0; i < 4; i++)
                #pragma unroll
                for (int r = 0; r < 4; r++) {
                    int m = m0 + wm * 64 + i * 16 + q * 4 + r;
                    part[(size_t)sl * (MTOK * NEXP) + (size_t)m * NEXP + e] = p[i][r];
                }
        }
    }
}

// --- Kernel 2: deterministic sum of 32 slices -> logits, top-2, softmax ---
__global__ __launch_bounds__(256) void router_topk(
    const float* __restrict__ part, const float* __restrict__ b2,
    float* __restrict__ out, float* __restrict__ gu, int* __restrict__ gc)
{
    const int t = blockIdx.x * 256 + threadIdx.x;

    float logit[8];
    #pragma unroll
    for (int e = 0; e < 8; e++) logit[e] = b2[e];
    #pragma unroll
    for (int j = 0; j < NSLC; j++) {
        const float4* p4 = (const float4*)(part + (size_t)j * (MTOK * NEXP) + (size_t)t * NEXP);
        float4 u = p4[0], v = p4[1];
        logit[0] += u.x; logit[1] += u.y; logit[2] += u.z; logit[3] += u.w;
        logit[4] += v.x; logit[5] += v.y; logit[6] += v.z; logit[7] += v.w;
    }

    int i1 = 0; float v1 = logit[0];
    #pragma unroll
    for (int e = 1; e < 8; e++) { if (logit[e] > v1) { v1 = logit[e]; i1 = e; } }
    int i2 = -1; float v2 = -INFINITY;
    #pragma unroll
    for (int e = 0; e < 8; e++) {
        if (e != i1 && logit[e] > v2) { v2 = logit[e]; i2 = e; }
    }
    float ex = expf(v2 - v1);
    float inv = 1.0f / (1.0f + ex);
    float wa = inv, wb = ex * inv;

    float4* o = (float4*)(out + (size_t)t * NEXP);
    o[0] = make_float4(logit[0], logit[1], logit[2], logit[3]);
    o[1] = make_float4(logit[4], logit[5], logit[6], logit[7]);

    float mk[8];
    #pragma unroll
    for (int e = 0; e < 8; e++) mk[e] = 0.0f;
    mk[i1] = wa; mk[i2] = wb;
    float4* om = (float4*)(out + (size_t)(MTOK * NEXP) + (size_t)t * NEXP);
    om[0] = make_float4(mk[0], mk[1], mk[2], mk[3]);
    om[1] = make_float4(mk[4], mk[5], mk[6], mk[7]);

    __shared__ float us[8];
    __shared__ int cs;
    if (threadIdx.x < 8) us[threadIdx.x] = 0.0f;
    if (threadIdx.x == 0) cs = 0;
    __syncthreads();
    atomicAdd(&us[i1], wa);
    atomicAdd(&us[i2], wb);
    int cnt = (wa > 0.0f ? 1 : 0) + (wb > 0.0f ? 1 : 0);
    atomicAdd(&cs, cnt);
    __syncthreads();
    if (threadIdx.x < 8) atomicAdd(&gu[threadIdx.x], us[threadIdx.x]);
    if (threadIdx.x == 0) atomicAdd(gc, cs);
}

// --- Kernel 3: finalize losses + normalized usage ---
__global__ void router_final(const float* __restrict__ gu, const int* __restrict__ gc,
                             float* __restrict__ out)
{
    if (blockIdx.x == 0 && threadIdx.x == 0) {
        float u[8]; float tot = 0.0f;
        for (int e = 0; e < 8; e++) { u[e] = gu[e]; tot += u[e]; }
        float lb = 0.0f;
        for (int e = 0; e < 8; e++) {
            float un = u[e] / tot;
            out[2 * MTOK * NEXP + 1 + e] = un;
            float d = un - 0.125f;
            lb += d * d;
        }
        lb *= (1.0f / 8.0f);
        float sp = ((float)(*gc) / (float)MTOK) * 0.5f;
        out[2 * MTOK * NEXP] = lb + 0.1f * sp;
    }
}

extern "C" void kernel_launch(void* const* d_in, const int* in_sizes, int n_in,
                              void* d_out, int out_size, void* d_ws, size_t ws_size,
                              hipStream_t stream) {
    const float* x  = (const float*)d_in[0];
    const float* w1 = (const float*)d_in[1];
    const float* b1 = (const float*)d_in[2];
    const float* w2 = (const float*)d_in[3];
    const float* b2 = (const float*)d_in[4];
    float* out = (float*)d_out;

    unsigned short* af = (unsigned short*)d_ws;            // 1024*32768*2 B = 64 MiB
    unsigned short* wf = af + (size_t)1024 * 32768;        // 8 MiB
    float* part = (float*)(wf + (size_t)128 * 32 * 1024);  // 16 MiB
    float* gu = part + (size_t)NSLC * MTOK * NEXP;
    int* gc = (int*)(gu + 8);

    hipMemsetAsync(gu, 0, 64, stream);

    cvt_x<<<1024, 256, 0, stream>>>(x, af);
    cvt_w1f<<<dim3(FDIM / 32, HDIM / 32), 256, 0, stream>>>(w1, wf);
    gemm1_mfma<<<2048, 256, 0, stream>>>(af, wf, b1, w2, part);
    router_topk<<<MTOK / 256, 256, 0, stream>>>(part, b2, out, gu, gc);
    router_final<<<1, 64, 0, stream>>>(gu, gc, out);
}